// Round 3
// baseline (935.930 us; speedup 1.0000x reference)
//
#include <hip/hip_runtime.h>
#include <hip/hip_bf16.h>

#define NP    4096
#define DFEAT 512

using bf16x8 = __attribute__((ext_vector_type(8))) short;
using f32x4  = __attribute__((ext_vector_type(4))) float;

static __device__ __forceinline__ f32x4 mfma16(bf16x8 a, bf16x8 b, f32x4 c) {
    return __builtin_amdgcn_mfma_f32_16x16x32_bf16(a, b, c, 0, 0, 0);
}
static __device__ __forceinline__ f32x4 zero4() { f32x4 z = {0.f,0.f,0.f,0.f}; return z; }

// element-index XOR swizzle for [64][64] bf16 tiles: spreads the 128B row
// stride across 8 distinct 16B slots -> 2-way max on ds_read_b128 (free).
static __device__ __forceinline__ int SWZ(int row, int col) {
    return (row * 64 + col) ^ ((row & 7) << 3);
}

static __device__ __forceinline__ unsigned short f2bf(float f) {
    __hip_bfloat16 h = __float2bfloat16(f);
    return reinterpret_cast<unsigned short&>(h);
}

// ---- streaming fp32 -> bf16 conversion of x, w_qkv, proj_w ----
__global__ void convert_all(const float* __restrict__ x,
                            const float* __restrict__ wqkv,
                            const float* __restrict__ projw,
                            unsigned short* __restrict__ xb,
                            unsigned short* __restrict__ wqb,
                            unsigned short* __restrict__ pwb) {
    const int XQ = (8 * NP * DFEAT) / 4;        // 4,194,304 quads
    const int WQ = (3 * DFEAT * DFEAT) / 4;     //   196,608
    const int PQ = (DFEAT * DFEAT) / 4;         //    65,536
    int i = blockIdx.x * blockDim.x + threadIdx.x;
    const float* src; unsigned short* dst; int j;
    if (i < XQ)            { src = x;     dst = xb;  j = i; }
    else if (i < XQ + WQ)  { src = wqkv;  dst = wqb; j = i - XQ; }
    else if (i < XQ + WQ + PQ) { src = projw; dst = pwb; j = i - XQ - WQ; }
    else return;
    float4 v = *(const float4*)(src + (size_t)j * 4);
    ushort4 o;
    o.x = f2bf(v.x); o.y = f2bf(v.y); o.z = f2bf(v.z); o.w = f2bf(v.w);
    *(ushort4*)(dst + (size_t)j * 4) = o;
}

__launch_bounds__(512, 6)
__global__ void seqwin_attn(const __hip_bfloat16* __restrict__ xb,
                            const __hip_bfloat16* __restrict__ wq_bf,
                            const __hip_bfloat16* __restrict__ pw_bf,
                            const float* __restrict__ proj_b,
                            float* __restrict__ out) {
    // [0]=Q (then P, then Oh)  [1]=K  [2]=V^T ; x2 heads per pair. 48 KB total.
    __shared__ __hip_bfloat16 smem[3][2][64 * 64];

    const int tid  = threadIdx.x;
    const int wid  = tid >> 6;      // 0..7
    const int lane = tid & 63;
    const int ln16 = lane & 15;
    const int lg   = lane >> 4;     // 0..3
    const int hq   = wid >> 2;      // head of pair this wave serves in attention
    const int wq   = wid & 3;       // wave within head-quad (owns q-rows wq*16..)

    const int bw = blockIdx.x;
    const int b  = bw >> 6;
    const int w  = bw & 63;
    const __hip_bfloat16* xtile = xb + ((size_t)b * NP + (size_t)w * 64) * DFEAT;

    f32x4 oacc[4][4];   // persistent: rows rt*16.., cols wid*64 + ct*16..
    #pragma unroll
    for (int i = 0; i < 4; ++i)
        #pragma unroll
        for (int j = 0; j < 4; ++j) oacc[i][j] = zero4();

    for (int hp = 0; hp < 4; ++hp) {
        const int h0 = hp * 2;

        // ---- phase 1: QKV GEMM, 24 col-tiles over 8 waves, ks-outer ----
        f32x4 acc[3][4];
        #pragma unroll
        for (int i = 0; i < 3; ++i)
            #pragma unroll
            for (int rt = 0; rt < 4; ++rt) acc[i][rt] = zero4();

        const __hip_bfloat16* brow[3];
        int t_[3], hh_[3], n0_[3];
        #pragma unroll
        for (int i = 0; i < 3; ++i) {
            int ct2 = wid + 8 * i;              // 0..23
            int hh  = (ct2 >= 12) ? 1 : 0;
            int rem = ct2 - 12 * hh;
            int tt  = rem >> 2;                 // 0=Q 1=K 2=V
            int n0  = (rem & 3) << 4;
            t_[i] = tt; hh_[i] = hh; n0_[i] = n0;
            brow[i] = wq_bf + ((size_t)(tt * DFEAT + (h0 + hh) * 64 + n0 + ln16)) * DFEAT;
        }
        #pragma unroll 4
        for (int ks = 0; ks < 16; ++ks) {
            int k0 = ks * 32 + lg * 8;
            bf16x8 a[4];
            #pragma unroll
            for (int rt = 0; rt < 4; ++rt)
                a[rt] = *(const bf16x8*)(xtile + (size_t)(rt * 16 + ln16) * DFEAT + k0);
            #pragma unroll
            for (int i = 0; i < 3; ++i) {
                bf16x8 bfr = *(const bf16x8*)(brow[i] + k0);
                #pragma unroll
                for (int rt = 0; rt < 4; ++rt)
                    acc[i][rt] = mfma16(a[rt], bfr, acc[i][rt]);
            }
        }
        #pragma unroll
        for (int i = 0; i < 3; ++i) {
            __hip_bfloat16* dst = &smem[t_[i]][hh_[i]][0];
            #pragma unroll
            for (int rt = 0; rt < 4; ++rt)
                #pragma unroll
                for (int j = 0; j < 4; ++j) {
                    int tok = rt * 16 + lg * 4 + j;
                    int d   = n0_[i] + ln16;
                    __hip_bfloat16 val = __float2bfloat16(acc[i][rt][j]);
                    if (t_[i] == 2) dst[SWZ(d, tok)] = val;   // V stored transposed
                    else            dst[SWZ(tok, d)] = val;
                }
        }
        __syncthreads();   // B1: QKV visible to all waves

        // ---- phase 2+3: S=QK^T, softmax, P, PV -> Oh  (no barrier inside:
        //      P/Oh live only in this wave's own 16-row slice of smem[0]) ----
        {
            f32x4 s[4];
            #pragma unroll
            for (int ct = 0; ct < 4; ++ct) s[ct] = zero4();
            #pragma unroll
            for (int ks = 0; ks < 2; ++ks) {
                int k0 = ks * 32 + lg * 8;
                bf16x8 qf = *(const bf16x8*)&smem[0][hq][SWZ(wq * 16 + ln16, k0)];
                #pragma unroll
                for (int ct = 0; ct < 4; ++ct) {
                    bf16x8 kf = *(const bf16x8*)&smem[1][hq][SWZ(ct * 16 + ln16, k0)];
                    s[ct] = mfma16(qf, kf, s[ct]);
                }
            }
            const float scale = 0.125f;   // DH^-0.5
            #pragma unroll
            for (int j = 0; j < 4; ++j) {
                float sv[4];
                float m = -1e30f;
                #pragma unroll
                for (int ct = 0; ct < 4; ++ct) { sv[ct] = s[ct][j] * scale; m = fmaxf(m, sv[ct]); }
                #pragma unroll
                for (int off = 1; off < 16; off <<= 1) m = fmaxf(m, __shfl_xor(m, off));
                float pv[4], sum = 0.f;
                #pragma unroll
                for (int ct = 0; ct < 4; ++ct) { pv[ct] = __expf(sv[ct] - m); sum += pv[ct]; }
                #pragma unroll
                for (int off = 1; off < 16; off <<= 1) sum += __shfl_xor(sum, off);
                float inv = 1.f / sum;
                int q = wq * 16 + lg * 4 + j;
                #pragma unroll
                for (int ct = 0; ct < 4; ++ct)
                    smem[0][hq][SWZ(q, ct * 16 + ln16)] = __float2bfloat16(pv[ct] * inv);
            }
            f32x4 o[4];
            #pragma unroll
            for (int ct = 0; ct < 4; ++ct) o[ct] = zero4();
            #pragma unroll
            for (int ks = 0; ks < 2; ++ks) {
                int k0 = ks * 32 + lg * 8;
                bf16x8 pf = *(const bf16x8*)&smem[0][hq][SWZ(wq * 16 + ln16, k0)];
                #pragma unroll
                for (int ct = 0; ct < 4; ++ct) {
                    bf16x8 vf = *(const bf16x8*)&smem[2][hq][SWZ(ct * 16 + ln16, k0)];
                    o[ct] = mfma16(pf, vf, o[ct]);
                }
            }
            #pragma unroll
            for (int ct = 0; ct < 4; ++ct)
                #pragma unroll
                for (int j = 0; j < 4; ++j)
                    smem[0][hq][SWZ(wq * 16 + lg * 4 + j, ct * 16 + ln16)] =
                        __float2bfloat16(o[ct][j]);
        }
        __syncthreads();   // B2: Oh visible to all waves

        // ---- phase 4: oacc += Oh @ projW^T slice, both heads ----
        #pragma unroll
        for (int hh = 0; hh < 2; ++hh) {
            #pragma unroll
            for (int ks = 0; ks < 2; ++ks) {
                int k0 = ks * 32 + lg * 8;
                bf16x8 a[4];
                #pragma unroll
                for (int rt = 0; rt < 4; ++rt)
                    a[rt] = *(const bf16x8*)&smem[0][hh][SWZ(rt * 16 + ln16, k0)];
                #pragma unroll
                for (int ct = 0; ct < 4; ++ct) {
                    const __hip_bfloat16* prow =
                        pw_bf + ((size_t)(wid * 64 + ct * 16 + ln16)) * DFEAT
                              + (h0 + hh) * 64 + k0;
                    bf16x8 bfr = *(const bf16x8*)prow;
                    #pragma unroll
                    for (int rt = 0; rt < 4; ++rt)
                        oacc[rt][ct] = mfma16(a[rt], bfr, oacc[rt][ct]);
                }
            }
        }
        __syncthreads();   // B3: smem free for next pair's QKV writes
    }

    // ---- epilogue: bias + fp32 store ----
    #pragma unroll
    for (int rt = 0; rt < 4; ++rt)
        #pragma unroll
        for (int ct = 0; ct < 4; ++ct) {
            int col = wid * 64 + ct * 16 + ln16;
            float bias = proj_b[col];
            #pragma unroll
            for (int j = 0; j < 4; ++j) {
                int tok = rt * 16 + lg * 4 + j;
                out[((size_t)b * NP + (size_t)w * 64 + tok) * DFEAT + col] =
                    oacc[rt][ct][j] + bias;
            }
        }
}

extern "C" void kernel_launch(void* const* d_in, const int* in_sizes, int n_in,
                              void* d_out, int out_size, void* d_ws, size_t ws_size,
                              hipStream_t stream) {
    const float* x      = (const float*)d_in[0];
    // d_in[1] (z) unused by the reference
    const float* w_qkv  = (const float*)d_in[2];
    const float* proj_w = (const float*)d_in[3];
    const float* proj_b = (const float*)d_in[4];
    float* outp = (float*)d_out;

    unsigned short* xb  = (unsigned short*)d_ws;            // 16,777,216 elems
    unsigned short* wqb = xb + (size_t)8 * NP * DFEAT;      //    786,432 elems
    unsigned short* pwb = wqb + 3 * DFEAT * DFEAT;          //    262,144 elems

    // 4,456,448 quads total -> exactly 8704 blocks of 512
    convert_all<<<8704, 512, 0, stream>>>(x, w_qkv, proj_w, xb, wqb, pwb);

    seqwin_attn<<<512, 512, 0, stream>>>((const __hip_bfloat16*)xb,
                                         (const __hip_bfloat16*)wqb,
                                         (const __hip_bfloat16*)pwb,
                                         proj_b, outp);
}

// Round 4
// 277.993 us; speedup vs baseline: 3.3667x; 3.3667x over previous
//
#include <hip/hip_runtime.h>
#include <hip/hip_bf16.h>
#include <stdint.h>

#define NP 4096
#define DF 512

using bf16x8 = __attribute__((ext_vector_type(8))) short;
using f32x4  = __attribute__((ext_vector_type(4))) float;

static __device__ __forceinline__ f32x4 mfma16(bf16x8 a, bf16x8 b, f32x4 c) {
    return __builtin_amdgcn_mfma_f32_16x16x32_bf16(a, b, c, 0, 0, 0);
}
static __device__ __forceinline__ f32x4 zero4() { f32x4 z = {0.f,0.f,0.f,0.f}; return z; }

// XOR swizzles: spread row-stride across 16B slots (2-way max on b128 reads)
static __device__ __forceinline__ int SWZ64(int row, int col) {   // [64][64] tiles
    return (row * 64 + col) ^ ((row & 7) << 3);
}
static __device__ __forceinline__ int SWZ256(int row, int col) {  // [64][256] tile
    return (row * 256 + col) ^ ((row & 7) << 3);
}

static __device__ __forceinline__ unsigned short f2bf(float f) {
    __hip_bfloat16 h = __float2bfloat16(f);
    return reinterpret_cast<unsigned short&>(h);
}

#define GLOAD_LDS16(gp, lp) __builtin_amdgcn_global_load_lds( \
    (const __attribute__((address_space(1))) uint32_t*)(gp), \
    (__attribute__((address_space(3))) uint32_t*)(lp), 16, 0, 0)

// ---- weights fp32 -> bf16 ----
__global__ void convert_weights(const float* __restrict__ wqkv,
                                const float* __restrict__ projw,
                                unsigned short* __restrict__ wqb,
                                unsigned short* __restrict__ pwb) {
    const int WQ = (3 * DF * DF) / 4;   // 196,608 quads
    const int PQ = (DF * DF) / 4;       //  65,536 quads
    int i = blockIdx.x * blockDim.x + threadIdx.x;
    const float* src; unsigned short* dst; int j;
    if (i < WQ)            { src = wqkv;  dst = wqb; j = i; }
    else if (i < WQ + PQ)  { src = projw; dst = pwb; j = i - WQ; }
    else return;
    float4 v = *(const float4*)(src + (size_t)j * 4);
    ushort4 o;
    o.x = f2bf(v.x); o.y = f2bf(v.y); o.z = f2bf(v.z); o.w = f2bf(v.w);
    *(ushort4*)(dst + (size_t)j * 4) = o;
}

// ==== Kernel 1: QKV projection + windowed attention -> aout (bf16) ====
__launch_bounds__(512, 4)
__global__ void qkv_attn(const float* __restrict__ x,
                         const __hip_bfloat16* __restrict__ wqb,
                         __hip_bfloat16* __restrict__ aout) {
    __shared__ __hip_bfloat16 xs[64 * 256];          // 32 KB: one K-half of x tile
    __shared__ __hip_bfloat16 smem[3][2][64 * 64];   // 48 KB: Q/K/V^T per head pair

    const int tid  = threadIdx.x;
    const int wid  = tid >> 6;
    const int lane = tid & 63;
    const int ln16 = lane & 15;
    const int lg   = lane >> 4;
    const int hq   = wid >> 2;     // head of pair in attention
    const int wq   = wid & 3;      // wave within head-quad

    const int b = blockIdx.x >> 6;
    const int w = blockIdx.x & 63;
    const float* xwin = x + ((size_t)b * NP + (size_t)w * 64) * DF;

    for (int hp = 0; hp < 4; ++hp) {
        const int h0 = hp * 2;

        // ---- phase 1: QKV GEMM, 24 col-tiles over 8 waves, ks-outer,
        //      x staged per K-half from fp32 global ----
        int t_[3], hh_[3], n0_[3];
        const __hip_bfloat16* brow[3];
        #pragma unroll
        for (int i = 0; i < 3; ++i) {
            int ct2 = wid + 8 * i;
            int hh  = (ct2 >= 12) ? 1 : 0;
            int rem = ct2 - 12 * hh;
            int tt  = rem >> 2;                 // 0=Q 1=K 2=V
            int n0  = (rem & 3) << 4;
            t_[i] = tt; hh_[i] = hh; n0_[i] = n0;
            brow[i] = wqb + ((size_t)(tt * DF + (h0 + hh) * 64 + n0 + ln16)) * DF;
        }
        f32x4 acc[3][4];
        #pragma unroll
        for (int i = 0; i < 3; ++i)
            #pragma unroll
            for (int rt = 0; rt < 4; ++rt) acc[i][rt] = zero4();

        #pragma unroll
        for (int kb = 0; kb < 2; ++kb) {
            // stage 64x256 fp32 half -> bf16 LDS, swizzled, fully coalesced
            #pragma unroll
            for (int it = 0; it < 8; ++it) {
                int f   = it * 512 + tid;      // float4 idx, 64 per row
                int row = f >> 6;
                int c4  = f & 63;
                float4 v = *(const float4*)(xwin + (size_t)row * DF + kb * 256 + c4 * 4);
                ushort4 o;
                o.x = f2bf(v.x); o.y = f2bf(v.y); o.z = f2bf(v.z); o.w = f2bf(v.w);
                *(ushort4*)&xs[SWZ256(row, c4 * 4)] = o;
            }
            __syncthreads();                   // staging visible
            #pragma unroll
            for (int ks = 0; ks < 8; ++ks) {
                int k0l = ks * 32 + lg * 8;    // col within half
                bf16x8 a[4];
                #pragma unroll
                for (int rt = 0; rt < 4; ++rt)
                    a[rt] = *(const bf16x8*)&xs[SWZ256(rt * 16 + ln16, k0l)];
                #pragma unroll
                for (int i = 0; i < 3; ++i) {
                    bf16x8 bfr = *(const bf16x8*)(brow[i] + kb * 256 + k0l);
                    #pragma unroll
                    for (int rt = 0; rt < 4; ++rt)
                        acc[i][rt] = mfma16(a[rt], bfr, acc[i][rt]);
                }
            }
            if (kb == 0) __syncthreads();      // xs readers done before restage
        }
        // write QKV -> smem (swizzled)
        #pragma unroll
        for (int i = 0; i < 3; ++i) {
            __hip_bfloat16* dst = &smem[t_[i]][hh_[i]][0];
            #pragma unroll
            for (int rt = 0; rt < 4; ++rt)
                #pragma unroll
                for (int j = 0; j < 4; ++j) {
                    int tok = rt * 16 + lg * 4 + j;
                    int d   = n0_[i] + ln16;
                    __hip_bfloat16 val = __float2bfloat16(acc[i][rt][j]);
                    if (t_[i] == 2) dst[SWZ64(d, tok)] = val;   // V transposed
                    else            dst[SWZ64(tok, d)] = val;
                }
        }
        __syncthreads();   // B1: QKV visible

        // ---- phase 2: attention (each wave: 16 q-rows of one head) ----
        {
            f32x4 s[4];
            #pragma unroll
            for (int ct = 0; ct < 4; ++ct) s[ct] = zero4();
            #pragma unroll
            for (int ks = 0; ks < 2; ++ks) {
                int k0 = ks * 32 + lg * 8;
                bf16x8 qf = *(const bf16x8*)&smem[0][hq][SWZ64(wq * 16 + ln16, k0)];
                #pragma unroll
                for (int ct = 0; ct < 4; ++ct) {
                    bf16x8 kf = *(const bf16x8*)&smem[1][hq][SWZ64(ct * 16 + ln16, k0)];
                    s[ct] = mfma16(qf, kf, s[ct]);
                }
            }
            const float scale = 0.125f;
            #pragma unroll
            for (int j = 0; j < 4; ++j) {
                float sv[4];
                float m = -1e30f;
                #pragma unroll
                for (int ct = 0; ct < 4; ++ct) { sv[ct] = s[ct][j] * scale; m = fmaxf(m, sv[ct]); }
                #pragma unroll
                for (int off = 1; off < 16; off <<= 1) m = fmaxf(m, __shfl_xor(m, off));
                float pv[4], sum = 0.f;
                #pragma unroll
                for (int ct = 0; ct < 4; ++ct) { pv[ct] = __expf(sv[ct] - m); sum += pv[ct]; }
                #pragma unroll
                for (int off = 1; off < 16; off <<= 1) sum += __shfl_xor(sum, off);
                float inv = 1.f / sum;
                int q = wq * 16 + lg * 4 + j;
                #pragma unroll
                for (int ct = 0; ct < 4; ++ct)
                    smem[0][hq][SWZ64(q, ct * 16 + ln16)] = __float2bfloat16(pv[ct] * inv);
            }
            f32x4 o[4];
            #pragma unroll
            for (int ct = 0; ct < 4; ++ct) o[ct] = zero4();
            #pragma unroll
            for (int ks = 0; ks < 2; ++ks) {
                int k0 = ks * 32 + lg * 8;
                bf16x8 pf = *(const bf16x8*)&smem[0][hq][SWZ64(wq * 16 + ln16, k0)];
                #pragma unroll
                for (int ct = 0; ct < 4; ++ct) {
                    bf16x8 vf = *(const bf16x8*)&smem[2][hq][SWZ64(ct * 16 + ln16, k0)];
                    o[ct] = mfma16(pf, vf, o[ct]);
                }
            }
            // Oh -> global (bf16), feat = head*64 + col
            #pragma unroll
            for (int ct = 0; ct < 4; ++ct)
                #pragma unroll
                for (int j = 0; j < 4; ++j) {
                    size_t tok = (size_t)b * NP + (size_t)w * 64 + wq * 16 + lg * 4 + j;
                    aout[tok * DF + (h0 + hq) * 64 + ct * 16 + ln16] =
                        __float2bfloat16(o[ct][j]);
                }
        }
        __syncthreads();   // B2: attn smem reads done before next pair's writes
    }
}

// ==== Kernel 2: out = aout @ proj_w^T + bias  (m97-style 128x128 tile) ====
__launch_bounds__(256, 4)
__global__ void proj_gemm(const __hip_bfloat16* __restrict__ A,    // [32768][512]
                          const __hip_bfloat16* __restrict__ Bt,   // pwb [512][512]
                          const float* __restrict__ bias,
                          float* __restrict__ out) {
    __shared__ __hip_bfloat16 As[128 * 64];   // 16 KB
    __shared__ __hip_bfloat16 Bs[128 * 64];   // 16 KB

    const int tid  = threadIdx.x;
    const int wid  = tid >> 6;      // 0..3
    const int lane = tid & 63;
    const int ln16 = lane & 15;
    const int lg   = lane >> 4;
    const int wr   = wid >> 1;      // 0..1: M-half
    const int wc   = wid & 1;       // 0..1: N-half

    const int mb = blockIdx.x >> 2;         // 0..255
    const int nb = blockIdx.x & 3;          // 0..3
    const int m0 = mb * 128;
    const int n0g = nb * 128;

    f32x4 acc[4][4];
    #pragma unroll
    for (int i = 0; i < 4; ++i)
        #pragma unroll
        for (int j = 0; j < 4; ++j) acc[i][j] = zero4();

    const int srow = (lane >> 3);       // 0..7 within segment
    const int scol = (lane & 7) * 8;    // elem offset 0..56

    for (int kt = 0; kt < 8; ++kt) {
        int k0 = kt * 64;
        #pragma unroll
        for (int it = 0; it < 4; ++it) {
            int s   = wid * 4 + it;         // segment 0..15, 8 rows each
            int row = s * 8 + srow;
            GLOAD_LDS16(A  + (size_t)(m0  + row) * DF + k0 + scol, &As[s * 512]);
            GLOAD_LDS16(Bt + (size_t)(n0g + row) * DF + k0 + scol, &Bs[s * 512]);
        }
        __syncthreads();   // compiler drains vmcnt before barrier
        #pragma unroll
        for (int kk = 0; kk < 2; ++kk) {
            int kl = kk * 32 + lg * 8;
            bf16x8 af[4], bfr[4];
            #pragma unroll
            for (int rt = 0; rt < 4; ++rt)
                af[rt] = *(const bf16x8*)&As[(wr * 64 + rt * 16 + ln16) * 64 + kl];
            #pragma unroll
            for (int ct = 0; ct < 4; ++ct)
                bfr[ct] = *(const bf16x8*)&Bs[(wc * 64 + ct * 16 + ln16) * 64 + kl];
            #pragma unroll
            for (int rt = 0; rt < 4; ++rt)
                #pragma unroll
                for (int ct = 0; ct < 4; ++ct)
                    acc[rt][ct] = mfma16(af[rt], bfr[ct], acc[rt][ct]);
        }
        __syncthreads();
    }

    #pragma unroll
    for (int ct = 0; ct < 4; ++ct) {
        int col = n0g + wc * 64 + ct * 16 + ln16;
        float bv = bias[col];
        #pragma unroll
        for (int rt = 0; rt < 4; ++rt)
            #pragma unroll
            for (int j = 0; j < 4; ++j)
                out[(size_t)(m0 + wr * 64 + rt * 16 + lg * 4 + j) * DF + col] =
                    acc[rt][ct][j] + bv;
    }
}

extern "C" void kernel_launch(void* const* d_in, const int* in_sizes, int n_in,
                              void* d_out, int out_size, void* d_ws, size_t ws_size,
                              hipStream_t stream) {
    const float* x      = (const float*)d_in[0];
    // d_in[1] (z) unused by the reference
    const float* w_qkv  = (const float*)d_in[2];
    const float* proj_w = (const float*)d_in[3];
    const float* proj_b = (const float*)d_in[4];
    float* outp = (float*)d_out;

    __hip_bfloat16* aout = (__hip_bfloat16*)d_ws;                      // 32 MB
    unsigned short* wqb  = (unsigned short*)(aout + (size_t)8 * NP * DF);
    unsigned short* pwb  = wqb + 3 * DF * DF;

    convert_weights<<<512, 512, 0, stream>>>(w_qkv, proj_w, wqb, pwb);

    qkv_attn<<<512, 512, 0, stream>>>(x, (const __hip_bfloat16*)wqb, aout);

    proj_gemm<<<1024, 256, 0, stream>>>(aout, (const __hip_bfloat16*)pwb,
                                        proj_b, outp);
}

// Round 5
// 270.877 us; speedup vs baseline: 3.4552x; 1.0263x over previous
//
#include <hip/hip_runtime.h>
#include <hip/hip_bf16.h>
#include <stdint.h>

#define NP 4096
#define DF 512

using bf16x8 = __attribute__((ext_vector_type(8))) short;
using f32x4  = __attribute__((ext_vector_type(4))) float;

static __device__ __forceinline__ f32x4 mfma16(bf16x8 a, bf16x8 b, f32x4 c) {
    return __builtin_amdgcn_mfma_f32_16x16x32_bf16(a, b, c, 0, 0, 0);
}
static __device__ __forceinline__ f32x4 zero4() { f32x4 z = {0.f,0.f,0.f,0.f}; return z; }

// element-index XOR swizzle for [64][64] bf16 tiles (QKV/attention buffers)
static __device__ __forceinline__ int SWZ64(int row, int col) {
    return (row * 64 + col) ^ ((row & 7) << 3);
}

static __device__ __forceinline__ unsigned short f2bf(float f) {
    __hip_bfloat16 h = __float2bfloat16(f);
    return reinterpret_cast<unsigned short&>(h);
}

#define GLOAD_LDS16(gp, lp) __builtin_amdgcn_global_load_lds( \
    (const __attribute__((address_space(1))) uint32_t*)(gp), \
    (__attribute__((address_space(3))) uint32_t*)(lp), 16, 0, 0)

// ---- streaming fp32 -> bf16 conversion of x, w_qkv, proj_w ----
__global__ void convert_all(const float* __restrict__ x,
                            const float* __restrict__ wqkv,
                            const float* __restrict__ projw,
                            unsigned short* __restrict__ xb,
                            unsigned short* __restrict__ wqb,
                            unsigned short* __restrict__ pwb) {
    const int XQ = (8 * NP * DF) / 4;        // 4,194,304 quads
    const int WQ = (3 * DF * DF) / 4;        //   196,608
    const int PQ = (DF * DF) / 4;            //    65,536
    int i = blockIdx.x * blockDim.x + threadIdx.x;
    const float* src; unsigned short* dst; int j;
    if (i < XQ)                { src = x;     dst = xb;  j = i; }
    else if (i < XQ + WQ)      { src = wqkv;  dst = wqb; j = i - XQ; }
    else if (i < XQ + WQ + PQ) { src = projw; dst = pwb; j = i - XQ - WQ; }
    else return;
    float4 v = *(const float4*)(src + (size_t)j * 4);
    ushort4 o;
    o.x = f2bf(v.x); o.y = f2bf(v.y); o.z = f2bf(v.z); o.w = f2bf(v.w);
    *(ushort4*)(dst + (size_t)j * 4) = o;
}

// ==== Kernel 1: QKV projection + windowed attention -> aout (bf16) ====
// LDS 80 KB -> 2 blocks/CU. Register peak ~95 (unified) -> no spill at cap 128.
__launch_bounds__(512, 4)
__global__ void qkv_attn(const __hip_bfloat16* __restrict__ xb,
                         const __hip_bfloat16* __restrict__ wqb,
                         __hip_bfloat16* __restrict__ aout) {
    __shared__ __hip_bfloat16 xs[64 * 256];          // 32 KB: one K-half of x tile
    __shared__ __hip_bfloat16 smem[3][2][64 * 64];   // 48 KB: Q/K/V^T per head pair

    const int tid  = threadIdx.x;
    const int wid  = tid >> 6;
    const int lane = tid & 63;
    const int ln16 = lane & 15;
    const int lg   = lane >> 4;
    const int hq   = wid >> 2;     // head of pair in attention
    const int wq   = wid & 3;      // wave within head-quad

    const int b = blockIdx.x >> 6;
    const int w = blockIdx.x & 63;
    const __hip_bfloat16* xwin = xb + ((size_t)b * NP + (size_t)w * 64) * DF;

    for (int hp = 0; hp < 4; ++hp) {
        const int h0 = hp * 2;

        // B-row pointers for this wave's 3 col-tiles (of 24 = 2 heads x {Q,K,V} x 4)
        const __hip_bfloat16* brow[3];
        #pragma unroll
        for (int i = 0; i < 3; ++i) {
            int ct2 = wid + 8 * i;
            int hh  = (ct2 >= 12) ? 1 : 0;
            int rem = ct2 - 12 * hh;
            int tt  = rem >> 2;
            int n0  = (rem & 3) << 4;
            brow[i] = wqb + ((size_t)(tt * DF + (h0 + hh) * 64 + n0 + ln16)) * DF;
        }
        f32x4 acc[3][4];
        #pragma unroll
        for (int i = 0; i < 3; ++i)
            #pragma unroll
            for (int rt = 0; rt < 4; ++rt) acc[i][rt] = zero4();

        #pragma unroll
        for (int kb = 0; kb < 2; ++kb) {
            // stage 64x256 bf16 K-half via global_load_lds, pre-swizzled source:
            // LDS linear chunk slot (row,c) holds global chunk (c ^ (row&7))
            #pragma unroll
            for (int it = 0; it < 4; ++it) {
                int slot = it * 512 + tid;      // 2048 chunks of 16B
                int row  = slot >> 5;           // 32 chunks per row
                int c    = slot & 31;
                int gc   = c ^ (row & 7);
                GLOAD_LDS16(xwin + (size_t)row * DF + kb * 256 + gc * 8,
                            &xs[(size_t)slot * 8]);
            }
            __syncthreads();                    // vmcnt drained by compiler
            #pragma unroll
            for (int ks = 0; ks < 8; ++ks) {
                int c0  = ks * 4 + lg;          // 16B chunk index within row
                int k0l = ks * 32 + lg * 8;
                bf16x8 a[4];
                #pragma unroll
                for (int rt = 0; rt < 4; ++rt) {
                    int r = rt * 16 + ln16;
                    a[rt] = *(const bf16x8*)&xs[(r << 8) + ((c0 ^ (r & 7)) << 3)];
                }
                #pragma unroll
                for (int i = 0; i < 3; ++i) {
                    bf16x8 bfr = *(const bf16x8*)(brow[i] + kb * 256 + k0l);
                    #pragma unroll
                    for (int rt = 0; rt < 4; ++rt)
                        acc[i][rt] = mfma16(a[rt], bfr, acc[i][rt]);
                }
            }
            if (kb == 0) __syncthreads();       // xs readers done before restage
        }
        // write QKV -> smem (swizzled); recompute tile ids (saves live regs)
        #pragma unroll
        for (int i = 0; i < 3; ++i) {
            int ct2 = wid + 8 * i;
            int hh  = (ct2 >= 12) ? 1 : 0;
            int rem = ct2 - 12 * hh;
            int tt  = rem >> 2;
            int n0  = (rem & 3) << 4;
            __hip_bfloat16* dst = &smem[tt][hh][0];
            #pragma unroll
            for (int rt = 0; rt < 4; ++rt)
                #pragma unroll
                for (int j = 0; j < 4; ++j) {
                    int tok = rt * 16 + lg * 4 + j;
                    int d   = n0 + ln16;
                    __hip_bfloat16 val = __float2bfloat16(acc[i][rt][j]);
                    if (tt == 2) dst[SWZ64(d, tok)] = val;   // V transposed
                    else         dst[SWZ64(tok, d)] = val;
                }
        }
        __syncthreads();   // B1: QKV visible

        // ---- attention: each wave owns 16 q-rows of one head ----
        {
            f32x4 s[4];
            #pragma unroll
            for (int ct = 0; ct < 4; ++ct) s[ct] = zero4();
            #pragma unroll
            for (int ks = 0; ks < 2; ++ks) {
                int k0 = ks * 32 + lg * 8;
                bf16x8 qf = *(const bf16x8*)&smem[0][hq][SWZ64(wq * 16 + ln16, k0)];
                #pragma unroll
                for (int ct = 0; ct < 4; ++ct) {
                    bf16x8 kf = *(const bf16x8*)&smem[1][hq][SWZ64(ct * 16 + ln16, k0)];
                    s[ct] = mfma16(qf, kf, s[ct]);
                }
            }
            const float scale = 0.125f;
            #pragma unroll
            for (int j = 0; j < 4; ++j) {
                float sv[4];
                float m = -1e30f;
                #pragma unroll
                for (int ct = 0; ct < 4; ++ct) { sv[ct] = s[ct][j] * scale; m = fmaxf(m, sv[ct]); }
                #pragma unroll
                for (int off = 1; off < 16; off <<= 1) m = fmaxf(m, __shfl_xor(m, off));
                float pv[4], sum = 0.f;
                #pragma unroll
                for (int ct = 0; ct < 4; ++ct) { pv[ct] = __expf(sv[ct] - m); sum += pv[ct]; }
                #pragma unroll
                for (int off = 1; off < 16; off <<= 1) sum += __shfl_xor(sum, off);
                float inv = 1.f / sum;
                int q = wq * 16 + lg * 4 + j;
                #pragma unroll
                for (int ct = 0; ct < 4; ++ct)
                    smem[0][hq][SWZ64(q, ct * 16 + ln16)] = __float2bfloat16(pv[ct] * inv);
            }
            f32x4 o[4];
            #pragma unroll
            for (int ct = 0; ct < 4; ++ct) o[ct] = zero4();
            #pragma unroll
            for (int ks = 0; ks < 2; ++ks) {
                int k0 = ks * 32 + lg * 8;
                bf16x8 pf = *(const bf16x8*)&smem[0][hq][SWZ64(wq * 16 + ln16, k0)];
                #pragma unroll
                for (int ct = 0; ct < 4; ++ct) {
                    bf16x8 vf = *(const bf16x8*)&smem[2][hq][SWZ64(ct * 16 + ln16, k0)];
                    o[ct] = mfma16(pf, vf, o[ct]);
                }
            }
            #pragma unroll
            for (int ct = 0; ct < 4; ++ct)
                #pragma unroll
                for (int j = 0; j < 4; ++j) {
                    size_t tok = (size_t)b * NP + (size_t)w * 64 + wq * 16 + lg * 4 + j;
                    aout[tok * DF + (h0 + hq) * 64 + ct * 16 + ln16] =
                        __float2bfloat16(o[ct][j]);
                }
        }
        __syncthreads();   // B2: attn reads done before next pair's writes
    }
}

// ==== Kernel 2: out = aout @ proj_w^T + bias (128x128 tile, swizzled LDS) ====
__launch_bounds__(256, 4)
__global__ void proj_gemm(const __hip_bfloat16* __restrict__ A,    // [32768][512]
                          const __hip_bfloat16* __restrict__ Bt,   // pwb [512][512]
                          const float* __restrict__ bias,
                          float* __restrict__ out) {
    __shared__ __hip_bfloat16 As[128 * 64];   // 16 KB, chunk-swizzled
    __shared__ __hip_bfloat16 Bs[128 * 64];   // 16 KB

    const int tid  = threadIdx.x;
    const int wid  = tid >> 6;      // 0..3
    const int lane = tid & 63;
    const int ln16 = lane & 15;
    const int lg   = lane >> 4;
    const int wr   = wid >> 1;      // M-half
    const int wc   = wid & 1;       // N-half

    const int mb = blockIdx.x >> 2;
    const int nb = blockIdx.x & 3;
    const int m0 = mb * 128;
    const int n0g = nb * 128;

    f32x4 acc[4][4];
    #pragma unroll
    for (int i = 0; i < 4; ++i)
        #pragma unroll
        for (int j = 0; j < 4; ++j) acc[i][j] = zero4();

    for (int kt = 0; kt < 8; ++kt) {
        int k0 = kt * 64;
        #pragma unroll
        for (int it = 0; it < 4; ++it) {
            int slot = it * 256 + tid;          // 1024 chunk slots of 16B
            int row  = slot >> 3;               // 8 chunks per row
            int c    = slot & 7;
            int gc   = (c ^ (row & 7)) * 8;     // pre-swizzled source elem offset
            GLOAD_LDS16(A  + (size_t)(m0  + row) * DF + k0 + gc, &As[slot * 8]);
            GLOAD_LDS16(Bt + (size_t)(n0g + row) * DF + k0 + gc, &Bs[slot * 8]);
        }
        __syncthreads();
        #pragma unroll
        for (int kk = 0; kk < 2; ++kk) {
            int c0 = kk * 4 + lg;               // chunk within row
            bf16x8 af[4], bfr[4];
            #pragma unroll
            for (int rt = 0; rt < 4; ++rt) {
                int r = wr * 64 + rt * 16 + ln16;
                af[rt] = *(const bf16x8*)&As[(r << 6) + ((c0 ^ (r & 7)) << 3)];
            }
            #pragma unroll
            for (int ct = 0; ct < 4; ++ct) {
                int r = wc * 64 + ct * 16 + ln16;
                bfr[ct] = *(const bf16x8*)&Bs[(r << 6) + ((c0 ^ (r & 7)) << 3)];
            }
            #pragma unroll
            for (int rt = 0; rt < 4; ++rt)
                #pragma unroll
                for (int ct = 0; ct < 4; ++ct)
                    acc[rt][ct] = mfma16(af[rt], bfr[ct], acc[rt][ct]);
        }
        __syncthreads();
    }

    #pragma unroll
    for (int ct = 0; ct < 4; ++ct) {
        int col = n0g + wc * 64 + ct * 16 + ln16;
        float bv = bias[col];
        #pragma unroll
        for (int rt = 0; rt < 4; ++rt)
            #pragma unroll
            for (int j = 0; j < 4; ++j)
                out[(size_t)(m0 + wr * 64 + rt * 16 + lg * 4 + j) * DF + col] =
                    acc[rt][ct][j] + bv;
    }
}

extern "C" void kernel_launch(void* const* d_in, const int* in_sizes, int n_in,
                              void* d_out, int out_size, void* d_ws, size_t ws_size,
                              hipStream_t stream) {
    const float* x      = (const float*)d_in[0];
    // d_in[1] (z) unused by the reference
    const float* w_qkv  = (const float*)d_in[2];
    const float* proj_w = (const float*)d_in[3];
    const float* proj_b = (const float*)d_in[4];
    float* outp = (float*)d_out;

    unsigned short* xb   = (unsigned short*)d_ws;               // 32 MB
    unsigned short* aoutw = xb + (size_t)8 * NP * DF;           // 32 MB
    unsigned short* wqb  = aoutw + (size_t)8 * NP * DF;         // 1.5 MB
    unsigned short* pwb  = wqb + 3 * DF * DF;                   // 0.5 MB

    // 4,456,448 quads -> 8704 blocks of 512
    convert_all<<<8704, 512, 0, stream>>>(x, w_qkv, proj_w, xb, wqb, pwb);

    qkv_attn<<<512, 512, 0, stream>>>((const __hip_bfloat16*)xb,
                                      (const __hip_bfloat16*)wqb,
                                      (__hip_bfloat16*)aoutw);

    proj_gemm<<<1024, 256, 0, stream>>>((const __hip_bfloat16*)aoutw,
                                        (const __hip_bfloat16*)pwb,
                                        proj_b, outp);
}

// Round 6
// 131.117 us; speedup vs baseline: 7.1381x; 2.0659x over previous
//
#include <hip/hip_runtime.h>
#include <hip/hip_bf16.h>
#include <stdint.h>

#define NP 4096
#define DF 512
#define NQ3 1536   // 3*DF

using bf16x8 = __attribute__((ext_vector_type(8))) short;
using f32x4  = __attribute__((ext_vector_type(4))) float;

static __device__ __forceinline__ f32x4 mfma16(bf16x8 a, bf16x8 b, f32x4 c) {
    return __builtin_amdgcn_mfma_f32_16x16x32_bf16(a, b, c, 0, 0, 0);
}
static __device__ __forceinline__ f32x4 zero4() { f32x4 z = {0.f,0.f,0.f,0.f}; return z; }

// element-index XOR swizzle for [64][64] bf16 tiles
static __device__ __forceinline__ int SWZ64(int row, int col) {
    return (row * 64 + col) ^ ((row & 7) << 3);
}

static __device__ __forceinline__ unsigned short f2bf(float f) {
    __hip_bfloat16 h = __float2bfloat16(f);
    return reinterpret_cast<unsigned short&>(h);
}

#define GLOAD_LDS16(gp, lp) __builtin_amdgcn_global_load_lds( \
    (const __attribute__((address_space(1))) uint32_t*)(gp), \
    (__attribute__((address_space(3))) uint32_t*)(lp), 16, 0, 0)

// ---- streaming fp32 -> bf16 conversion of x, w_qkv, proj_w ----
__global__ void convert_all(const float* __restrict__ x,
                            const float* __restrict__ wqkv,
                            const float* __restrict__ projw,
                            unsigned short* __restrict__ xb,
                            unsigned short* __restrict__ wqb,
                            unsigned short* __restrict__ pwb) {
    const int XQ = (8 * NP * DF) / 4;        // 4,194,304 quads
    const int WQ = (3 * DF * DF) / 4;        //   196,608
    const int PQ = (DF * DF) / 4;            //    65,536
    int i = blockIdx.x * blockDim.x + threadIdx.x;
    const float* src; unsigned short* dst; int j;
    if (i < XQ)                { src = x;     dst = xb;  j = i; }
    else if (i < XQ + WQ)      { src = wqkv;  dst = wqb; j = i - XQ; }
    else if (i < XQ + WQ + PQ) { src = projw; dst = pwb; j = i - XQ - WQ; }
    else return;
    float4 v = *(const float4*)(src + (size_t)j * 4);
    ushort4 o;
    o.x = f2bf(v.x); o.y = f2bf(v.y); o.z = f2bf(v.z); o.w = f2bf(v.w);
    *(ushort4*)(dst + (size_t)j * 4) = o;
}

// ==== K2: qkv = xb @ wqb^T   (M=32768, N=1536, K=512, bf16 out) ====
// m97-style 128x128 tile, 4 waves, gload_lds staging, swizzled LDS.
__launch_bounds__(256, 2)
__global__ void qkv_gemm(const __hip_bfloat16* __restrict__ A,   // [32768][512]
                         const __hip_bfloat16* __restrict__ Bt,  // [1536][512]
                         unsigned short* __restrict__ C) {       // [32768][1536]
    __shared__ __hip_bfloat16 As[128 * 64];   // 16 KB, chunk-swizzled
    __shared__ __hip_bfloat16 Bs[128 * 64];

    const int tid  = threadIdx.x;
    const int wid  = tid >> 6;
    const int lane = tid & 63;
    const int ln16 = lane & 15;
    const int lg   = lane >> 4;
    const int wr   = wid >> 1;
    const int wc   = wid & 1;

    // XCD-chunked work swizzle: 3072 blocks, 8 XCDs, 384 per XCD.
    // nb-inner ordering -> one XCD handles a contiguous mb range (A-panel L2 reuse).
    int wk = (blockIdx.x & 7) * 384 + (blockIdx.x >> 3);
    const int m0 = (wk / 12) * 128;
    const int n0 = (wk % 12) * 128;

    f32x4 acc[4][4];
    #pragma unroll
    for (int i = 0; i < 4; ++i)
        #pragma unroll
        for (int j = 0; j < 4; ++j) acc[i][j] = zero4();

    for (int kt = 0; kt < 8; ++kt) {
        int k0 = kt * 64;
        #pragma unroll
        for (int it = 0; it < 4; ++it) {
            int slot = it * 256 + tid;          // 1024 chunks of 16B
            int row  = slot >> 3;               // 8 chunks per row
            int c    = slot & 7;
            int gc   = (c ^ (row & 7)) * 8;     // pre-swizzled source
            GLOAD_LDS16(A  + (size_t)(m0 + row) * DF + k0 + gc, &As[slot * 8]);
            GLOAD_LDS16(Bt + (size_t)(n0 + row) * DF + k0 + gc, &Bs[slot * 8]);
        }
        __syncthreads();
        #pragma unroll
        for (int kk = 0; kk < 2; ++kk) {
            int c0 = kk * 4 + lg;
            bf16x8 af[4], bfr[4];
            #pragma unroll
            for (int rt = 0; rt < 4; ++rt) {
                int r = wr * 64 + rt * 16 + ln16;
                af[rt] = *(const bf16x8*)&As[(r << 6) + ((c0 ^ (r & 7)) << 3)];
            }
            #pragma unroll
            for (int ct = 0; ct < 4; ++ct) {
                int r = wc * 64 + ct * 16 + ln16;
                bfr[ct] = *(const bf16x8*)&Bs[(r << 6) + ((c0 ^ (r & 7)) << 3)];
            }
            #pragma unroll
            for (int rt = 0; rt < 4; ++rt)
                #pragma unroll
                for (int ct = 0; ct < 4; ++ct)
                    acc[rt][ct] = mfma16(af[rt], bfr[ct], acc[rt][ct]);
        }
        __syncthreads();
    }

    #pragma unroll
    for (int rt = 0; rt < 4; ++rt)
        #pragma unroll
        for (int ct = 0; ct < 4; ++ct)
            #pragma unroll
            for (int j = 0; j < 4; ++j)
                C[(size_t)(m0 + wr * 64 + rt * 16 + lg * 4 + j) * NQ3
                  + n0 + wc * 64 + ct * 16 + ln16] = f2bf(acc[rt][ct][j]);
}

// ==== K3: windowed attention. One wave = one (head, window). No barriers. ====
__launch_bounds__(256, 2)
__global__ void attn(const __hip_bfloat16* __restrict__ qkv,   // [32768][1536]
                     unsigned short* __restrict__ aout) {      // [32768][512]
    // per wave: [0] = P (64x64), [1] = V^T (64x64); wave-private -> no syncs
    __shared__ unsigned short lds[4][2][64 * 64];   // 64 KB

    const int tid  = threadIdx.x;
    const int wid  = tid >> 6;
    const int lane = tid & 63;
    const int ln16 = lane & 15;
    const int lg   = lane >> 4;

    const int blk = blockIdx.x;          // 1024 = (b*64+w)*2 + half
    const int bw  = blk >> 1;
    const int hh  = (blk & 1) * 4 + wid; // head 0..7
    const size_t tokbase = (size_t)bw * 64;
    const __hip_bfloat16* base = qkv + tokbase * NQ3;

    // ---- V -> V^T in LDS (coalesced global reads, swizzled scalar writes) ----
    #pragma unroll
    for (int rt = 0; rt < 4; ++rt)
        #pragma unroll
        for (int ks = 0; ks < 2; ++ks) {
            bf16x8 vf = *(const bf16x8*)(base + (size_t)(rt * 16 + ln16) * NQ3
                                         + 2 * DF + hh * 64 + ks * 32 + lg * 8);
            #pragma unroll
            for (int i = 0; i < 8; ++i) {
                int d = ks * 32 + lg * 8 + i;
                lds[wid][1][SWZ64(d, rt * 16 + ln16)] = (unsigned short)vf[i];
            }
        }

    // ---- K fragments (held in regs across the S phase) ----
    bf16x8 kf[4][2];
    #pragma unroll
    for (int ct = 0; ct < 4; ++ct)
        #pragma unroll
        for (int ks = 0; ks < 2; ++ks)
            kf[ct][ks] = *(const bf16x8*)(base + (size_t)(ct * 16 + ln16) * NQ3
                                          + DF + hh * 64 + ks * 32 + lg * 8);

    // ---- per 16-row strip: S = scale*Q K^T, softmax, P -> LDS ----
    const float scale = 0.125f;
    #pragma unroll
    for (int rt = 0; rt < 4; ++rt) {
        bf16x8 qf[2];
        #pragma unroll
        for (int ks = 0; ks < 2; ++ks)
            qf[ks] = *(const bf16x8*)(base + (size_t)(rt * 16 + ln16) * NQ3
                                      + hh * 64 + ks * 32 + lg * 8);
        f32x4 s[4];
        #pragma unroll
        for (int ct = 0; ct < 4; ++ct) s[ct] = zero4();
        #pragma unroll
        for (int ks = 0; ks < 2; ++ks)
            #pragma unroll
            for (int ct = 0; ct < 4; ++ct)
                s[ct] = mfma16(qf[ks], kf[ct][ks], s[ct]);
        #pragma unroll
        for (int j = 0; j < 4; ++j) {
            float sv[4];
            float m = -1e30f;
            #pragma unroll
            for (int ct = 0; ct < 4; ++ct) { sv[ct] = s[ct][j] * scale; m = fmaxf(m, sv[ct]); }
            #pragma unroll
            for (int off = 1; off < 16; off <<= 1) m = fmaxf(m, __shfl_xor(m, off));
            float pv[4], sum = 0.f;
            #pragma unroll
            for (int ct = 0; ct < 4; ++ct) { pv[ct] = __expf(sv[ct] - m); sum += pv[ct]; }
            #pragma unroll
            for (int off = 1; off < 16; off <<= 1) sum += __shfl_xor(sum, off);
            float inv = 1.f / sum;
            int q = rt * 16 + lg * 4 + j;
            #pragma unroll
            for (int ct = 0; ct < 4; ++ct)
                lds[wid][0][SWZ64(q, ct * 16 + ln16)] = f2bf(pv[ct] * inv);
        }
    }

    // ---- V^T fragments (regs), then O = P V per strip ----
    bf16x8 vtf[4][2];
    #pragma unroll
    for (int ct = 0; ct < 4; ++ct)
        #pragma unroll
        for (int ks = 0; ks < 2; ++ks)
            vtf[ct][ks] = *(const bf16x8*)&lds[wid][1][SWZ64(ct * 16 + ln16,
                                                             ks * 32 + lg * 8)];
    #pragma unroll
    for (int rt = 0; rt < 4; ++rt) {
        bf16x8 pf[2];
        #pragma unroll
        for (int ks = 0; ks < 2; ++ks)
            pf[ks] = *(const bf16x8*)&lds[wid][0][SWZ64(rt * 16 + ln16,
                                                        ks * 32 + lg * 8)];
        f32x4 o[4];
        #pragma unroll
        for (int ct = 0; ct < 4; ++ct) o[ct] = zero4();
        #pragma unroll
        for (int ks = 0; ks < 2; ++ks)
            #pragma unroll
            for (int ct = 0; ct < 4; ++ct)
                o[ct] = mfma16(pf[ks], vtf[ct][ks], o[ct]);
        #pragma unroll
        for (int ct = 0; ct < 4; ++ct)
            #pragma unroll
            for (int j = 0; j < 4; ++j)
                aout[(tokbase + rt * 16 + lg * 4 + j) * DF + hh * 64
                     + ct * 16 + ln16] = f2bf(o[ct][j]);
    }
}

// ==== K4: out = aout @ proj_w^T + bias (128x128 tile, swizzled LDS) ====
__launch_bounds__(256, 4)
__global__ void proj_gemm(const __hip_bfloat16* __restrict__ A,    // [32768][512]
                          const __hip_bfloat16* __restrict__ Bt,   // [512][512]
                          const float* __restrict__ bias,
                          float* __restrict__ out) {
    __shared__ __hip_bfloat16 As[128 * 64];
    __shared__ __hip_bfloat16 Bs[128 * 64];

    const int tid  = threadIdx.x;
    const int wid  = tid >> 6;
    const int lane = tid & 63;
    const int ln16 = lane & 15;
    const int lg   = lane >> 4;
    const int wr   = wid >> 1;
    const int wc   = wid & 1;

    // XCD-chunked swizzle: 1024 blocks -> 128 per XCD, nb-inner
    int wk = (blockIdx.x & 7) * 128 + (blockIdx.x >> 3);
    const int m0  = (wk >> 2) * 128;
    const int n0g = (wk & 3) * 128;

    f32x4 acc[4][4];
    #pragma unroll
    for (int i = 0; i < 4; ++i)
        #pragma unroll
        for (int j = 0; j < 4; ++j) acc[i][j] = zero4();

    for (int kt = 0; kt < 8; ++kt) {
        int k0 = kt * 64;
        #pragma unroll
        for (int it = 0; it < 4; ++it) {
            int slot = it * 256 + tid;
            int row  = slot >> 3;
            int c    = slot & 7;
            int gc   = (c ^ (row & 7)) * 8;
            GLOAD_LDS16(A  + (size_t)(m0  + row) * DF + k0 + gc, &As[slot * 8]);
            GLOAD_LDS16(Bt + (size_t)(n0g + row) * DF + k0 + gc, &Bs[slot * 8]);
        }
        __syncthreads();
        #pragma unroll
        for (int kk = 0; kk < 2; ++kk) {
            int c0 = kk * 4 + lg;
            bf16x8 af[4], bfr[4];
            #pragma unroll
            for (int rt = 0; rt < 4; ++rt) {
                int r = wr * 64 + rt * 16 + ln16;
                af[rt] = *(const bf16x8*)&As[(r << 6) + ((c0 ^ (r & 7)) << 3)];
            }
            #pragma unroll
            for (int ct = 0; ct < 4; ++ct) {
                int r = wc * 64 + ct * 16 + ln16;
                bfr[ct] = *(const bf16x8*)&Bs[(r << 6) + ((c0 ^ (r & 7)) << 3)];
            }
            #pragma unroll
            for (int rt = 0; rt < 4; ++rt)
                #pragma unroll
                for (int ct = 0; ct < 4; ++ct)
                    acc[rt][ct] = mfma16(af[rt], bfr[ct], acc[rt][ct]);
        }
        __syncthreads();
    }

    #pragma unroll
    for (int ct = 0; ct < 4; ++ct) {
        int col = n0g + wc * 64 + ct * 16 + ln16;
        float bv = bias[col];
        #pragma unroll
        for (int rt = 0; rt < 4; ++rt)
            #pragma unroll
            for (int j = 0; j < 4; ++j)
                out[(size_t)(m0 + wr * 64 + rt * 16 + lg * 4 + j) * DF + col] =
                    acc[rt][ct][j] + bv;
    }
}

extern "C" void kernel_launch(void* const* d_in, const int* in_sizes, int n_in,
                              void* d_out, int out_size, void* d_ws, size_t ws_size,
                              hipStream_t stream) {
    const float* x      = (const float*)d_in[0];
    // d_in[1] (z) unused by the reference
    const float* w_qkv  = (const float*)d_in[2];
    const float* proj_w = (const float*)d_in[3];
    const float* proj_b = (const float*)d_in[4];
    float* outp = (float*)d_out;

    const size_t NTOK = (size_t)8 * NP;                 // 32768
    unsigned short* xb   = (unsigned short*)d_ws;       // 32 MB (reused as aout)
    unsigned short* qkvb = xb + NTOK * DF;              // 96 MB
    unsigned short* wqb  = qkvb + NTOK * NQ3;           // 1.5 MB
    unsigned short* pwb  = wqb + 3 * DF * DF;           // 0.5 MB
    unsigned short* aout = xb;                          // xb dead after qkv_gemm

    convert_all<<<8704, 512, 0, stream>>>(x, w_qkv, proj_w, xb, wqb, pwb);

    qkv_gemm<<<3072, 256, 0, stream>>>((const __hip_bfloat16*)xb,
                                       (const __hip_bfloat16*)wqb, qkvb);

    attn<<<1024, 256, 0, stream>>>((const __hip_bfloat16*)qkvb, aout);

    proj_gemm<<<1024, 256, 0, stream>>>((const __hip_bfloat16*)aout,
                                        (const __hip_bfloat16*)pwb,
                                        proj_b, outp);
}